// Round 1
// baseline (2452.639 us; speedup 1.0000x reference)
//
#include <hip/hip_runtime.h>
#include <math.h>

#define KCODES 1024
#define DDIM   256
#define NROWS  65536
#define BM     64
#define NT     256

// LDS layout for the z-tile: A[d][row-group swizzled]. Element (d, r) lives at
//   d*64 + ((r>>2) ^ ((d>>2)&15))*4 + (r&3)
// - compute read A[d][rg*4..rg*4+3] is a 16B-aligned ds_read_b128, conflict-free
// - staging writes / znorm reads land <=2-way (free per m136)
__device__ __forceinline__ int swz(int d, int r) {
    return d * 64 + ((((r) >> 2) ^ ((d >> 2) & 15)) << 2) + (r & 3);
}

// Prep: enorm[k] = sum_d e[d][k]^2 (sequential over d, matching np axis-0 reduce),
// eT[k][d] = e[d][k] (so the gather is a coalesced row read), zero the loss acc.
__global__ __launch_bounds__(NT) void prep_kernel(const float* __restrict__ e,
                                                  float* __restrict__ enorm,
                                                  float* __restrict__ eT,
                                                  float* __restrict__ loss_acc) {
    int k = blockIdx.x * blockDim.x + threadIdx.x;
    if (k == 0) *loss_acc = 0.f;
    if (k < KCODES) {
        float s = 0.f;
        for (int d = 0; d < DDIM; ++d) {
            float v = e[(size_t)d * KCODES + k];   // coalesced across k
            s = __fadd_rn(s, __fmul_rn(v, v));     // no FMA contraction: mimic np
            eT[(size_t)k * DDIM + d] = v;
        }
        enorm[k] = s;
    }
}

__global__ __launch_bounds__(NT) void vq_main(const float* __restrict__ z,
                                              const float* __restrict__ e,
                                              const float* __restrict__ enorm,
                                              const float* __restrict__ eT,
                                              float* __restrict__ out_zq,
                                              float* __restrict__ out_idx,
                                              float* __restrict__ loss_acc) {
    __shared__ __align__(16) float A[DDIM * BM];  // 64 KiB z-tile, [d][row] swizzled
    __shared__ float zn_s[BM];
    __shared__ float rv_s[BM * 16];
    __shared__ int   ri_s[BM * 16];
    __shared__ int   kmin_s[BM];
    __shared__ float wsum_s[4];

    const int tid  = threadIdx.x;
    const int lane = tid & 63;
    const int wv   = tid >> 6;          // wave id 0..3
    const int row0 = blockIdx.x * BM;

    // ---- stage z tile: per pass, each wave loads one row contiguously (1 KiB) ----
    for (int p = 0; p < 16; ++p) {
        const int row = p * 4 + wv;
        const int d0  = lane * 4;
        const float4 v = *reinterpret_cast<const float4*>(z + (size_t)(row0 + row) * DDIM + d0);
        A[swz(d0 + 0, row)] = v.x;
        A[swz(d0 + 1, row)] = v.y;
        A[swz(d0 + 2, row)] = v.z;
        A[swz(d0 + 3, row)] = v.w;
    }
    __syncthreads();

    // ---- ||z||^2 per row, replicating numpy pairwise_sum order for n=256:
    //      two 128-halves; each: 8 stride-8 partials, combine ((r0+r1)+(r2+r3))+((r4+r5)+(r6+r7))
    if (tid < BM) {
        const int r = tid;
        float hsum[2];
        #pragma unroll
        for (int h = 0; h < 2; ++h) {
            const int base = h * 128;
            float rp[8];
            #pragma unroll
            for (int j = 0; j < 8; ++j) {
                float v = A[swz(base + j, r)];
                rp[j] = __fmul_rn(v, v);
            }
            for (int i = 8; i < 128; i += 8) {
                #pragma unroll
                for (int j = 0; j < 8; ++j) {
                    float v = A[swz(base + i + j, r)];
                    rp[j] = __fadd_rn(rp[j], __fmul_rn(v, v));
                }
            }
            hsum[h] = __fadd_rn(__fadd_rn(__fadd_rn(rp[0], rp[1]), __fadd_rn(rp[2], rp[3])),
                                __fadd_rn(__fadd_rn(rp[4], rp[5]), __fadd_rn(rp[6], rp[7])));
        }
        zn_s[r] = __fadd_rn(hsum[0], hsum[1]);
    }
    __syncthreads();

    // ---- fused GEMM + running argmin: 4 rows x 4 cols per thread ----
    const int rg = tid >> 4;   // row group: rows rg*4 .. rg*4+3
    const int cg = tid & 15;   // col group within a 64-wide code tile

    float rmin[4] = {INFINITY, INFINITY, INFINITY, INFINITY};
    int   ridx[4] = {0, 0, 0, 0};

    for (int ct = 0; ct < KCODES / 64; ++ct) {
        const int c0 = ct * 64 + cg * 4;
        float acc[4][4];
        #pragma unroll
        for (int j = 0; j < 4; ++j)
            #pragma unroll
            for (int i = 0; i < 4; ++i) acc[j][i] = 0.f;

        const float* bp = e + c0;
        #pragma unroll 4
        for (int d = 0; d < DDIM; ++d) {
            const float4 b = *reinterpret_cast<const float4*>(bp + (size_t)d * KCODES);
            const float4 a = *reinterpret_cast<const float4*>(
                &A[d * 64 + ((rg ^ ((d >> 2) & 15)) << 2)]);
            acc[0][0] = fmaf(a.x, b.x, acc[0][0]);
            acc[0][1] = fmaf(a.x, b.y, acc[0][1]);
            acc[0][2] = fmaf(a.x, b.z, acc[0][2]);
            acc[0][3] = fmaf(a.x, b.w, acc[0][3]);
            acc[1][0] = fmaf(a.y, b.x, acc[1][0]);
            acc[1][1] = fmaf(a.y, b.y, acc[1][1]);
            acc[1][2] = fmaf(a.y, b.z, acc[1][2]);
            acc[1][3] = fmaf(a.y, b.w, acc[1][3]);
            acc[2][0] = fmaf(a.z, b.x, acc[2][0]);
            acc[2][1] = fmaf(a.z, b.y, acc[2][1]);
            acc[2][2] = fmaf(a.z, b.z, acc[2][2]);
            acc[2][3] = fmaf(a.z, b.w, acc[2][3]);
            acc[3][0] = fmaf(a.w, b.x, acc[3][0]);
            acc[3][1] = fmaf(a.w, b.y, acc[3][1]);
            acc[3][2] = fmaf(a.w, b.z, acc[3][2]);
            acc[3][3] = fmaf(a.w, b.w, acc[3][3]);
        }

        // epilogue: d = fl(fl(zn + enorm) - 2*dot), exact ref rounding (2*dot exact)
        #pragma unroll
        for (int j = 0; j < 4; ++j) {
            const float zn = zn_s[rg * 4 + j];
            #pragma unroll
            for (int i = 0; i < 4; ++i) {
                const int c = c0 + i;
                const float t = __fadd_rn(zn, enorm[c]);
                const float s = __fmaf_rn(-2.f, acc[j][i], t);
                if (s < rmin[j] || (s == rmin[j] && c < ridx[j])) { rmin[j] = s; ridx[j] = c; }
            }
        }
    }

    // ---- cross-thread argmin reduce (16 col-groups per row), min-index on ties ----
    #pragma unroll
    for (int j = 0; j < 4; ++j) {
        rv_s[(rg * 4 + j) * 16 + cg] = rmin[j];
        ri_s[(rg * 4 + j) * 16 + cg] = ridx[j];
    }
    __syncthreads();
    if (tid < BM) {
        float bv = INFINITY; int bi = 0x7fffffff;
        for (int t = 0; t < 16; ++t) {
            float v = rv_s[tid * 16 + t];
            int  id = ri_s[tid * 16 + t];
            if (v < bv || (v == bv && id < bi)) { bv = v; bi = id; }
        }
        kmin_s[tid] = bi;
        out_idx[row0 + tid] = (float)bi;   // harness reads whole buffer as f32
    }
    __syncthreads();

    // ---- gather z_q rows (coalesced via eT), write out, accumulate loss ----
    float part = 0.f;
    for (int p = 0; p < 16; ++p) {
        const int row = p * 4 + wv;
        const int d0  = lane * 4;
        const int kk  = kmin_s[row];
        const float4 q = *reinterpret_cast<const float4*>(eT + (size_t)kk * DDIM + d0);
        const float z0 = A[swz(d0 + 0, row)];
        const float z1 = A[swz(d0 + 1, row)];
        const float z2 = A[swz(d0 + 2, row)];
        const float z3 = A[swz(d0 + 3, row)];
        float dx;
        dx = q.x - z0; part = fmaf(dx, dx, part);
        dx = q.y - z1; part = fmaf(dx, dx, part);
        dx = q.z - z2; part = fmaf(dx, dx, part);
        dx = q.w - z3; part = fmaf(dx, dx, part);
        *reinterpret_cast<float4*>(out_zq + (size_t)(row0 + row) * DDIM + d0) = q;
    }
    #pragma unroll
    for (int off = 32; off > 0; off >>= 1) part += __shfl_down(part, off);
    if (lane == 0) wsum_s[wv] = part;
    __syncthreads();
    if (tid == 0)
        atomicAdd(loss_acc, (wsum_s[0] + wsum_s[1]) + (wsum_s[2] + wsum_s[3]));
}

__global__ void finalize_kernel(const float* __restrict__ loss_acc,
                                float* __restrict__ out_loss) {
    const float m = __fdiv_rn(*loss_acc, 16777216.f);           // mean
    out_loss[0] = __fadd_rn(__fmul_rn(0.25f, m), m);            // beta*m + m
}

extern "C" void kernel_launch(void* const* d_in, const int* in_sizes, int n_in,
                              void* d_out, int out_size, void* d_ws, size_t ws_size,
                              hipStream_t stream) {
    const float* z = (const float*)d_in[0];        // [65536, 256]
    const float* e = (const float*)d_in[1];        // [256, 1024]

    float* out_zq   = (float*)d_out;               // 16777216 floats
    float* out_idx  = out_zq + (size_t)NROWS * DDIM; // 65536 floats (index values)
    float* out_loss = out_idx + NROWS;             // 1 float

    float* loss_acc = (float*)d_ws;                            // 4 B
    float* enorm    = (float*)((char*)d_ws + 256);             // 4 KiB
    float* eT       = (float*)((char*)d_ws + 8192);            // 1 MiB

    prep_kernel<<<KCODES / NT, NT, 0, stream>>>(e, enorm, eT, loss_acc);
    vq_main<<<NROWS / BM, NT, 0, stream>>>(z, e, enorm, eT, out_zq, out_idx, loss_acc);
    finalize_kernel<<<1, 1, 0, stream>>>(loss_acc, out_loss);
}

// Round 2
// 703.296 us; speedup vs baseline: 3.4873x; 3.4873x over previous
//
#include <hip/hip_runtime.h>
#include <math.h>

#define KCODES 1024
#define DDIM   256
#define NROWS  65536
#define BM     64
#define NT     512

// LDS layout for the z-tile: element (d, r) at
//   d*64 + ((r>>2) ^ ((d>>2)&15))*4 + (r&3)
// - inner-loop read (fixed d, 2 row-groups per wave) = 2 broadcast b128, conflict-free
// - staging b32 writes land 8-way (one-time, negligible)
__device__ __forceinline__ int swz(int d, int r) {
    return (d << 6) + ((((r) >> 2) ^ ((d >> 2) & 15)) << 2) + (r & 3);
}

// ||e_k||^2 (sequential over d like before — rounding delta ~1e-11, irrelevant) + zero loss acc
__global__ __launch_bounds__(256) void enorm_kernel(const float* __restrict__ e,
                                                    float* __restrict__ enorm,
                                                    float* __restrict__ loss_acc) {
    const int k = blockIdx.x * 256 + threadIdx.x;
    if (k == 0) *loss_acc = 0.f;
    float s = 0.f;
    for (int d = 0; d < DDIM; ++d) {
        const float v = e[(size_t)d * KCODES + k];
        s = __fadd_rn(s, __fmul_rn(v, v));
    }
    enorm[k] = s;
}

// eT[k][d] = e[d][k]; one block per d-row, coalesced reads, scattered 4B writes (one-time)
__global__ __launch_bounds__(256) void etrans_kernel(const float* __restrict__ e,
                                                     float* __restrict__ eT) {
    const int d = blockIdx.x;
    const int t = threadIdx.x;
    const float4 v = *reinterpret_cast<const float4*>(e + (size_t)d * KCODES + t * 4);
    eT[(size_t)(t * 4 + 0) * DDIM + d] = v.x;
    eT[(size_t)(t * 4 + 1) * DDIM + d] = v.y;
    eT[(size_t)(t * 4 + 2) * DDIM + d] = v.z;
    eT[(size_t)(t * 4 + 3) * DDIM + d] = v.w;
}

__global__ __launch_bounds__(NT, 4) void vq_main(const float* __restrict__ z,
                                                 const float* __restrict__ e,
                                                 const float* __restrict__ enorm,
                                                 const float* __restrict__ eT,
                                                 float* __restrict__ out_zq,
                                                 float* __restrict__ out_idx,
                                                 float* __restrict__ loss_acc) {
    __shared__ __align__(16) float A[DDIM * BM];  // 64 KiB z-tile, swizzled
    __shared__ float zn_s[BM];
    __shared__ int   kmin_s[BM];
    __shared__ float wsum_s[8];

    const int tid  = threadIdx.x;
    const int lane = tid & 63;
    const int wv   = tid >> 6;          // wave 0..7
    const int row0 = blockIdx.x * BM;

    // ---- stage z tile: each wave loads one row (1 KiB) per pass, 8 passes ----
    for (int p = 0; p < 8; ++p) {
        const int row = p * 8 + wv;
        const int d0  = lane * 4;
        const float4 v = *reinterpret_cast<const float4*>(z + (size_t)(row0 + row) * DDIM + d0);
        A[swz(d0 + 0, row)] = v.x;
        A[swz(d0 + 1, row)] = v.y;
        A[swz(d0 + 2, row)] = v.z;
        A[swz(d0 + 3, row)] = v.w;
    }
    __syncthreads();

    // ---- ||z||^2 per row, numpy pairwise order (two 128-halves, 8 stride-8 partials) ----
    if (tid < BM) {
        const int r = tid;
        float hsum[2];
        #pragma unroll
        for (int h = 0; h < 2; ++h) {
            const int base = h * 128;
            float rp[8];
            #pragma unroll
            for (int j = 0; j < 8; ++j) {
                const float v = A[swz(base + j, r)];
                rp[j] = __fmul_rn(v, v);
            }
            for (int i = 8; i < 128; i += 8) {
                #pragma unroll
                for (int j = 0; j < 8; ++j) {
                    const float v = A[swz(base + i + j, r)];
                    rp[j] = __fadd_rn(rp[j], __fmul_rn(v, v));
                }
            }
            hsum[h] = __fadd_rn(__fadd_rn(__fadd_rn(rp[0], rp[1]), __fadd_rn(rp[2], rp[3])),
                                __fadd_rn(__fadd_rn(rp[4], rp[5]), __fadd_rn(rp[6], rp[7])));
        }
        zn_s[r] = __fadd_rn(hsum[0], hsum[1]);
    }
    __syncthreads();

    // ---- fused GEMM + running argmin ----
    // 512 threads: rg = tid>>5 (16 groups x 4 rows), cg = tid&31 (32 groups x 4 cols)
    // per ct: C-tile 64 rows x 128 cols; 8 ct iterations cover K=1024
    const int rg = tid >> 5;
    const int cg = tid & 31;

    float rmin[4] = {INFINITY, INFINITY, INFINITY, INFINITY};
    int   ridx[4] = {0, 0, 0, 0};

    for (int ct = 0; ct < 8; ++ct) {
        const int c0 = (ct << 7) + (cg << 2);
        const float4 en4 = *reinterpret_cast<const float4*>(enorm + c0);  // issued early
        const float* __restrict__ bp = e + c0;

        float acc[4][4];
        #pragma unroll
        for (int jj = 0; jj < 4; ++jj)
            #pragma unroll
            for (int i = 0; i < 4; ++i) acc[jj][i] = 0.f;

        for (int db = 0; db < DDIM; db += 16) {
            // batch 16 B-loads (64 VGPRs in flight; compiler emits counted vmcnt)
            float4 bb[16];
            #pragma unroll
            for (int j = 0; j < 16; ++j)
                bb[j] = *reinterpret_cast<const float4*>(bp + (size_t)((db + j) << 10));
            // 4 sub-groups of 4 d: one LDS base each, imm-offset b128 reads
            #pragma unroll
            for (int s = 0; s < 4; ++s) {
                const int t = ((db >> 2) + s) & 15;
                const float* ap = &A[((db + (s << 2)) << 6) + ((rg ^ t) << 2)];
                #pragma unroll
                for (int j = 0; j < 4; ++j) {
                    const float4 a = *reinterpret_cast<const float4*>(ap + (j << 6));
                    const float4 b = bb[(s << 2) | j];
                    acc[0][0] = fmaf(a.x, b.x, acc[0][0]);
                    acc[0][1] = fmaf(a.x, b.y, acc[0][1]);
                    acc[0][2] = fmaf(a.x, b.z, acc[0][2]);
                    acc[0][3] = fmaf(a.x, b.w, acc[0][3]);
                    acc[1][0] = fmaf(a.y, b.x, acc[1][0]);
                    acc[1][1] = fmaf(a.y, b.y, acc[1][1]);
                    acc[1][2] = fmaf(a.y, b.z, acc[1][2]);
                    acc[1][3] = fmaf(a.y, b.w, acc[1][3]);
                    acc[2][0] = fmaf(a.z, b.x, acc[2][0]);
                    acc[2][1] = fmaf(a.z, b.y, acc[2][1]);
                    acc[2][2] = fmaf(a.z, b.z, acc[2][2]);
                    acc[2][3] = fmaf(a.z, b.w, acc[2][3]);
                    acc[3][0] = fmaf(a.w, b.x, acc[3][0]);
                    acc[3][1] = fmaf(a.w, b.y, acc[3][1]);
                    acc[3][2] = fmaf(a.w, b.z, acc[3][2]);
                    acc[3][3] = fmaf(a.w, b.w, acc[3][3]);
                }
            }
        }

        // epilogue: d = fl(fl(zn + enorm) - 2*dot); strict < keeps first-min (cols ascend)
        const float en[4] = {en4.x, en4.y, en4.z, en4.w};
        #pragma unroll
        for (int jj = 0; jj < 4; ++jj) {
            const float zn = zn_s[(rg << 2) + jj];
            #pragma unroll
            for (int i = 0; i < 4; ++i) {
                const float t = __fadd_rn(zn, en[i]);
                const float s = __fmaf_rn(-2.f, acc[jj][i], t);
                if (s < rmin[jj]) { rmin[jj] = s; ridx[jj] = c0 + i; }
            }
        }
    }

    // ---- col-reduce: each half-wave (32 lanes, same rg) owns 4 rows exclusively ----
    #pragma unroll
    for (int jj = 0; jj < 4; ++jj) {
        float bv = rmin[jj];
        int   bi = ridx[jj];
        #pragma unroll
        for (int mask = 16; mask >= 1; mask >>= 1) {
            const float ov = __shfl_xor(bv, mask);
            const int   oi = __shfl_xor(bi, mask);
            if (ov < bv || (ov == bv && oi < bi)) { bv = ov; bi = oi; }
        }
        if (cg == 0) {
            const int row = (rg << 2) + jj;
            kmin_s[row] = bi;
            out_idx[row0 + row] = (float)bi;
        }
    }
    __syncthreads();

    // ---- gather z_q rows (coalesced via eT), write out, accumulate loss ----
    float part = 0.f;
    for (int p = 0; p < 8; ++p) {
        const int row = p * 8 + wv;
        const int d0  = lane * 4;
        const int kk  = kmin_s[row];
        const float4 q = *reinterpret_cast<const float4*>(eT + (size_t)kk * DDIM + d0);
        const float z0 = A[swz(d0 + 0, row)];
        const float z1 = A[swz(d0 + 1, row)];
        const float z2 = A[swz(d0 + 2, row)];
        const float z3 = A[swz(d0 + 3, row)];
        float dx;
        dx = q.x - z0; part = fmaf(dx, dx, part);
        dx = q.y - z1; part = fmaf(dx, dx, part);
        dx = q.z - z2; part = fmaf(dx, dx, part);
        dx = q.w - z3; part = fmaf(dx, dx, part);
        *reinterpret_cast<float4*>(out_zq + (size_t)(row0 + row) * DDIM + d0) = q;
    }
    #pragma unroll
    for (int off = 32; off > 0; off >>= 1) part += __shfl_down(part, off);
    if (lane == 0) wsum_s[wv] = part;
    __syncthreads();
    if (tid == 0) {
        float s = 0.f;
        #pragma unroll
        for (int i = 0; i < 8; ++i) s += wsum_s[i];
        atomicAdd(loss_acc, s);
    }
}

__global__ void finalize_kernel(const float* __restrict__ loss_acc,
                                float* __restrict__ out_loss) {
    const float m = __fdiv_rn(*loss_acc, 16777216.f);           // mean
    out_loss[0] = __fadd_rn(__fmul_rn(0.25f, m), m);            // beta*m + m
}

extern "C" void kernel_launch(void* const* d_in, const int* in_sizes, int n_in,
                              void* d_out, int out_size, void* d_ws, size_t ws_size,
                              hipStream_t stream) {
    const float* z = (const float*)d_in[0];        // [65536, 256]
    const float* e = (const float*)d_in[1];        // [256, 1024]

    float* out_zq   = (float*)d_out;                 // 16777216 floats
    float* out_idx  = out_zq + (size_t)NROWS * DDIM; // 65536 floats (index values)
    float* out_loss = out_idx + NROWS;               // 1 float

    float* loss_acc = (float*)d_ws;                            // 4 B
    float* enorm    = (float*)((char*)d_ws + 256);             // 4 KiB
    float* eT       = (float*)((char*)d_ws + 8192);            // 1 MiB

    enorm_kernel<<<KCODES / 256, 256, 0, stream>>>(e, enorm, loss_acc);
    etrans_kernel<<<DDIM, 256, 0, stream>>>(e, eT);
    vq_main<<<NROWS / BM, NT, 0, stream>>>(z, e, enorm, eT, out_zq, out_idx, loss_acc);
    finalize_kernel<<<1, 1, 0, stream>>>(loss_acc, out_loss);
}

// Round 3
// 590.057 us; speedup vs baseline: 4.1566x; 1.1919x over previous
//
#include <hip/hip_runtime.h>
#include <math.h>

#define KCODES 1024
#define DDIM   256
#define NROWS  65536
#define BM     64
#define NT     512

typedef float f4 __attribute__((ext_vector_type(4)));

// LDS layout for the z-tile: element (d, r) at
//   d*64 + ((r>>2) ^ ((d>>2)&15))*4 + (r&3)
// Inner-loop read (fixed d, row-group g): b128 at ((g ^ tt)<<2) — wave-uniform
// address -> LDS broadcast, conflict-free.
__device__ __forceinline__ int swz(int d, int r) {
    return (d << 6) + ((((r) >> 2) ^ ((d >> 2) & 15)) << 2) + (r & 3);
}

// ||e_k||^2 sequential over d (matches np axis-0 reduce) + zero the loss acc
__global__ __launch_bounds__(256) void enorm_kernel(const float* __restrict__ e,
                                                    float* __restrict__ enorm,
                                                    float* __restrict__ loss_acc) {
    const int k = blockIdx.x * 256 + threadIdx.x;
    if (k == 0) *loss_acc = 0.f;
    float s = 0.f;
    for (int d = 0; d < DDIM; ++d) {
        const float v = e[(size_t)d * KCODES + k];
        s = __fadd_rn(s, __fmul_rn(v, v));
    }
    enorm[k] = s;
}

// LDS-tiled transpose: eT[k][d] = e[d][k]; f4 reads AND f4 writes (one-time, ~3 us)
__global__ __launch_bounds__(256) void etrans_kernel(const float* __restrict__ e,
                                                     float* __restrict__ eT) {
    __shared__ float tile[64][65];
    const int k0 = blockIdx.x << 6;   // 16
    const int d0 = blockIdx.y << 6;   // 4
    const int tr = threadIdx.x >> 4;  // 0..15
    const int tc = threadIdx.x & 15;  // 0..15
    #pragma unroll
    for (int p = 0; p < 4; ++p) {
        const int d = (p << 4) + tr;
        const f4 v = *reinterpret_cast<const f4*>(e + (size_t)(d0 + d) * KCODES + k0 + (tc << 2));
        tile[(tc << 2) + 0][d] = v[0];
        tile[(tc << 2) + 1][d] = v[1];
        tile[(tc << 2) + 2][d] = v[2];
        tile[(tc << 2) + 3][d] = v[3];
    }
    __syncthreads();
    #pragma unroll
    for (int p = 0; p < 4; ++p) {
        const int k = (p << 4) + tr;
        f4 w;
        w[0] = tile[k][(tc << 2) + 0];
        w[1] = tile[k][(tc << 2) + 1];
        w[2] = tile[k][(tc << 2) + 2];
        w[3] = tile[k][(tc << 2) + 3];
        *reinterpret_cast<f4*>(eT + (size_t)(k0 + k) * DDIM + d0 + (tc << 2)) = w;
    }
}

__global__ __launch_bounds__(NT, 4) void vq_main(const float* __restrict__ z,
                                                 const float* __restrict__ e,
                                                 const float* __restrict__ enorm,
                                                 const float* __restrict__ eT,
                                                 float* __restrict__ out_zq,
                                                 float* __restrict__ out_idx,
                                                 float* __restrict__ loss_acc) {
    __shared__ __align__(16) float A[DDIM * BM];  // 64 KiB z-tile, swizzled
    __shared__ float zn_s[BM];
    __shared__ int   kmin_s[BM];
    __shared__ float wsum_s[8];

    const int tid  = threadIdx.x;
    const int lane = tid & 63;
    const int wv   = tid >> 6;          // wave 0..7
    const int row0 = blockIdx.x * BM;

    // ---- stage z tile (nontemporal: read-once stream, don't evict e from L2) ----
    for (int p = 0; p < 8; ++p) {
        const int row = p * 8 + wv;
        const int d0  = lane * 4;
        const f4 v = __builtin_nontemporal_load(
            reinterpret_cast<const f4*>(z + (size_t)(row0 + row) * DDIM + d0));
        A[swz(d0 + 0, row)] = v[0];
        A[swz(d0 + 1, row)] = v[1];
        A[swz(d0 + 2, row)] = v[2];
        A[swz(d0 + 3, row)] = v[3];
    }
    __syncthreads();

    // ---- ||z||^2 per row, numpy pairwise order (two 128-halves, 8 stride-8 partials) ----
    if (tid < BM) {
        const int r = tid;
        float hsum[2];
        #pragma unroll
        for (int h = 0; h < 2; ++h) {
            const int base = h * 128;
            float rp[8];
            #pragma unroll
            for (int j = 0; j < 8; ++j) {
                const float v = A[swz(base + j, r)];
                rp[j] = __fmul_rn(v, v);
            }
            for (int i = 8; i < 128; i += 8) {
                #pragma unroll
                for (int j = 0; j < 8; ++j) {
                    const float v = A[swz(base + i + j, r)];
                    rp[j] = __fadd_rn(rp[j], __fmul_rn(v, v));
                }
            }
            hsum[h] = __fadd_rn(__fadd_rn(__fadd_rn(rp[0], rp[1]), __fadd_rn(rp[2], rp[3])),
                                __fadd_rn(__fadd_rn(rp[4], rp[5]), __fadd_rn(rp[6], rp[7])));
        }
        zn_s[r] = __fadd_rn(hsum[0], hsum[1]);
    }
    __syncthreads();

    // ---- fused GEMM + running argmin ----
    // wave wv owns rows wv*8..wv*8+7 (A = 2 broadcast b128/d); lane owns 4 cols
    // of a 256-wide tile: c0 = ct*256 + lane*4; 4 ct iterations cover K=1024.
    float rmin[8] = {INFINITY, INFINITY, INFINITY, INFINITY,
                     INFINITY, INFINITY, INFINITY, INFINITY};
    int   ridx[8] = {0, 0, 0, 0, 0, 0, 0, 0};

    const int g0 = wv << 1;            // row-group of rows wv*8..+3
    for (int ct = 0; ct < 4; ++ct) {
        const int c0 = (ct << 8) + (lane << 2);
        const f4 en4 = *reinterpret_cast<const f4*>(enorm + c0);
        const float* __restrict__ bp = e + c0;

        float acc[8][4];
        #pragma unroll
        for (int r = 0; r < 8; ++r)
            #pragma unroll
            for (int i = 0; i < 4; ++i) acc[r][i] = 0.f;

        for (int db = 0; db < DDIM; db += 8) {
            f4 bb[8];
            #pragma unroll
            for (int j = 0; j < 8; ++j)
                bb[j] = *reinterpret_cast<const f4*>(bp + (size_t)((db + j) << 10));
            #pragma unroll
            for (int j = 0; j < 8; ++j) {
                const int d  = db + j;
                const int tt = (d >> 2) & 15;
                const f4 a0 = *reinterpret_cast<const f4*>(&A[(d << 6) + (((g0 | 0) ^ tt) << 2)]);
                const f4 a1 = *reinterpret_cast<const f4*>(&A[(d << 6) + (((g0 | 1) ^ tt) << 2)]);
                const f4 b  = bb[j];
                #pragma unroll
                for (int r = 0; r < 4; ++r)
                    #pragma unroll
                    for (int i = 0; i < 4; ++i) {
                        acc[r][i]     = fmaf(a0[r], b[i], acc[r][i]);
                        acc[4 + r][i] = fmaf(a1[r], b[i], acc[4 + r][i]);
                    }
            }
        }

        // epilogue: d = fl(fl(zn + enorm) - 2*dot); strict < keeps first-min (cols ascend)
        #pragma unroll
        for (int r8 = 0; r8 < 8; ++r8) {
            const float zn = zn_s[(wv << 3) + r8];
            #pragma unroll
            for (int i = 0; i < 4; ++i) {
                const float t = __fadd_rn(zn, en4[i]);
                const float s = __fmaf_rn(-2.f, acc[r8][i], t);
                if (s < rmin[r8]) { rmin[r8] = s; ridx[r8] = c0 + i; }
            }
        }
    }

    // ---- per-row argmin reduce across the 64 lanes (value, then min index on ties) ----
    #pragma unroll
    for (int r8 = 0; r8 < 8; ++r8) {
        float bv = rmin[r8];
        int   bi = ridx[r8];
        #pragma unroll
        for (int mask = 32; mask >= 1; mask >>= 1) {
            const float ov = __shfl_xor(bv, mask);
            const int   oi = __shfl_xor(bi, mask);
            if (ov < bv || (ov == bv && oi < bi)) { bv = ov; bi = oi; }
        }
        if (lane == 0) {
            const int row = (wv << 3) + r8;
            kmin_s[row] = bi;
            out_idx[row0 + row] = (float)bi;
        }
    }
    __syncthreads();

    // ---- gather z_q rows (coalesced via eT), NT-store out, accumulate loss ----
    float part = 0.f;
    for (int p = 0; p < 8; ++p) {
        const int row = p * 8 + wv;
        const int d0  = lane * 4;
        const int kk  = kmin_s[row];
        const f4 q = *reinterpret_cast<const f4*>(eT + (size_t)kk * DDIM + d0);
        const float z0 = A[swz(d0 + 0, row)];
        const float z1 = A[swz(d0 + 1, row)];
        const float z2 = A[swz(d0 + 2, row)];
        const float z3 = A[swz(d0 + 3, row)];
        float dx;
        dx = q[0] - z0; part = fmaf(dx, dx, part);
        dx = q[1] - z1; part = fmaf(dx, dx, part);
        dx = q[2] - z2; part = fmaf(dx, dx, part);
        dx = q[3] - z3; part = fmaf(dx, dx, part);
        __builtin_nontemporal_store(q, reinterpret_cast<f4*>(out_zq + (size_t)(row0 + row) * DDIM + d0));
    }
    #pragma unroll
    for (int off = 32; off > 0; off >>= 1) part += __shfl_down(part, off);
    if (lane == 0) wsum_s[wv] = part;
    __syncthreads();
    if (tid == 0) {
        float s = 0.f;
        #pragma unroll
        for (int i = 0; i < 8; ++i) s += wsum_s[i];
        atomicAdd(loss_acc, s);
    }
}

__global__ void finalize_kernel(const float* __restrict__ loss_acc,
                                float* __restrict__ out_loss) {
    const float m = __fdiv_rn(*loss_acc, 16777216.f);           // mean
    out_loss[0] = __fadd_rn(__fmul_rn(0.25f, m), m);            // beta*m + m
}

extern "C" void kernel_launch(void* const* d_in, const int* in_sizes, int n_in,
                              void* d_out, int out_size, void* d_ws, size_t ws_size,
                              hipStream_t stream) {
    const float* z = (const float*)d_in[0];        // [65536, 256]
    const float* e = (const float*)d_in[1];        // [256, 1024]

    float* out_zq   = (float*)d_out;                 // 16777216 floats
    float* out_idx  = out_zq + (size_t)NROWS * DDIM; // 65536 floats (index values)
    float* out_loss = out_idx + NROWS;               // 1 float

    float* loss_acc = (float*)d_ws;                            // 4 B
    float* enorm    = (float*)((char*)d_ws + 256);             // 4 KiB
    float* eT       = (float*)((char*)d_ws + 8192);            // 1 MiB

    enorm_kernel<<<KCODES / 256, 256, 0, stream>>>(e, enorm, loss_acc);
    etrans_kernel<<<dim3(KCODES / 64, DDIM / 64), 256, 0, stream>>>(e, eT);
    vq_main<<<NROWS / BM, NT, 0, stream>>>(z, e, enorm, eT, out_zq, out_idx, loss_acc);
    finalize_kernel<<<1, 1, 0, stream>>>(loss_acc, out_loss);
}